// Round 12
// baseline (467.225 us; speedup 1.0000x reference)
//
#include <hip/hip_runtime.h>
#include <hip/hip_fp16.h>
#include <math.h>

// Problem constants (verified against reference setup_inputs)
#define NODES    50000
#define IN_CH    256
#define HID      128
#define HEADS    3
#define HC       64
#define OC       (HEADS*HC)   // 192
#define NEG_SLOPE 0.2f
#define NBK      391          // ceil(50000/128) buckets
#define BCAP     4096         // staging capacity per bucket (avg fill ~2046)

typedef _Float16 half8_t __attribute__((ext_vector_type(8)));
typedef _Float16 half4_t __attribute__((ext_vector_type(4)));
typedef float float4_t __attribute__((ext_vector_type(4)));

__device__ __forceinline__ float lrelu(float v) { return v > 0.f ? v : NEG_SLOPE * v; }

// monotone unsigned key for float max-atomics (fkey(finite) > 0, so memset-0 is identity)
__device__ __forceinline__ unsigned fkey(float f) {
    unsigned b = __float_as_uint(f);
    return (b & 0x80000000u) ? ~b : (b | 0x80000000u);
}
__device__ __forceinline__ float fdec(unsigned k) {
    unsigned b = (k & 0x80000000u) ? (k ^ 0x80000000u) : ~k;
    return __uint_as_float(b);
}

// ---------------- stage 1: bucket append (+ weight fp16-transpose prepass) ----------------
__global__ __launch_bounds__(256) void k_bucket(const int* __restrict__ src, const int* __restrict__ dst, int E,
                                                int* __restrict__ bcnt, unsigned* __restrict__ bstage,
                                                const float* __restrict__ W1, const float* __restrict__ W2,
                                                _Float16* __restrict__ W1t, _Float16* __restrict__ W2t) {
    int e = blockIdx.x * 256 + threadIdx.x;
    if (e < E) {
        int d = dst[e], s = src[e];
        int b = d >> 7;
        int pos = atomicAdd(&bcnt[b], 1);
        if (pos < BCAP)
            bstage[(size_t)b * BCAP + pos] = ((unsigned)(d & 127) << 16) | (unsigned)s;
    }
    if (e < IN_CH * HID) {
        int c = e >> 8, k = e & 255;                 // W1t[c][k] = W1[k][c]
        W1t[e] = (_Float16)W1[(size_t)k * HID + c];
    } else if (e < IN_CH * HID + HID * OC) {
        int u = e - IN_CH * HID;
        int c = u >> 7, k = u & 127;                 // W2t[c][k] = W2[k][c]
        W2t[u] = (_Float16)W2[(size_t)k * OC + c];
    }
}

// ---------------- stage 2: scan bucket counts (one 512-thread block, 8 waves) ----------------
__global__ __launch_bounds__(512) void k_bscan(const int* __restrict__ bcnt, int* __restrict__ bbase,
                                               int* __restrict__ off, int nbk, int n) {
    __shared__ int wsums[8];
    int tid = threadIdx.x, lane = tid & 63, wid = tid >> 6;
    int v = (tid < nbk) ? bcnt[tid] : 0;
    int incl = v;
    #pragma unroll
    for (int d = 1; d < 64; d <<= 1) {
        int t = __shfl_up(incl, d, 64);
        if (lane >= d) incl += t;
    }
    if (lane == 63) wsums[wid] = incl;
    __syncthreads();
    if (tid == 0) {
        int run = 0;
        #pragma unroll
        for (int j = 0; j < 8; j++) { int t = wsums[j]; wsums[j] = run; run += t; }
    }
    __syncthreads();
    int excl = wsums[wid] + incl - v;
    if (tid < nbk) bbase[tid] = excl;
    if (tid == nbk - 1) off[n] = excl + v;   // = E
}

// ---------------- stage 3: per-bucket counting sort -> csr, off, dinv ----------------
// Block b owns nodes [b*128, b*128+128). All their edges are in its staging bucket.
// csr writes land in one contiguous ~8KB region owned by this block (no cross-XCD bouncing).
__global__ __launch_bounds__(256) void k_bsort(const unsigned* __restrict__ bstage, const int* __restrict__ bcnt,
                                               const int* __restrict__ bbase, int* __restrict__ off,
                                               float* __restrict__ dinv, int* __restrict__ csr, int n) {
    __shared__ int cnt128[128], exc128[128], rank128[128];
    __shared__ int wtot;
    int b = blockIdx.x, tid = threadIdx.x;
    if (tid < 128) { cnt128[tid] = 0; rank128[tid] = 0; }
    __syncthreads();

    int cntE = bcnt[b];
    if (cntE > BCAP) cntE = BCAP;
    const unsigned* st = bstage + (size_t)b * BCAP;
    for (int i = tid; i < cntE; i += 256)
        atomicAdd(&cnt128[st[i] >> 16], 1);
    __syncthreads();

    int v = 0, incl = 0;
    if (tid < 128) {                       // waves 0,1 fully active
        v = cnt128[tid];
        incl = v;
        #pragma unroll
        for (int d = 1; d < 64; d <<= 1) {
            int t = __shfl_up(incl, d, 64);
            if ((tid & 63) >= d) incl += t;
        }
        if (tid == 63) wtot = incl;
    }
    __syncthreads();
    int base = bbase[b];
    if (tid < 128) {
        int excl = incl - v + (tid >= 64 ? wtot : 0);
        exc128[tid] = excl;
        int gd = b * 128 + tid;
        if (gd < n) {
            off[gd] = base + excl;
            dinv[gd] = rsqrtf((float)(v + 1));   // +1 for self loop
        }
    }
    __syncthreads();

    for (int i = tid; i < cntE; i += 256) {
        unsigned vv = st[i];
        int ld = vv >> 16, s = vv & 0xffff;
        int r = atomicAdd(&rank128[ld], 1);
        csr[base + exc128[ld] + r] = s;
    }
}

// ---------------- GEMM1 (MFMA): xwh = fp16( dinv[row] * (x @ W1) ) ----------------
__global__ __launch_bounds__(256) void k_gemm1m(const float* __restrict__ x, const _Float16* __restrict__ W1t,
                                                const float* __restrict__ dinv,
                                                _Float16* __restrict__ xwh, int n) {
    int wid = threadIdx.x >> 6, lane = threadIdx.x & 63;
    int lrow = lane & 15, kgrp = lane >> 4;          // A: row=lrow, k-chunk=kgrp*8
    int arow = blockIdx.x * 64 + wid * 16 + lrow;
    bool rv = arow < n;
    const float* xp = x + (size_t)arow * IN_CH + kgrp * 8;

    float4_t acc[8];
    #pragma unroll
    for (int s = 0; s < 8; s++) acc[s] = (float4_t)(0.f);

    #pragma unroll
    for (int kc = 0; kc < IN_CH; kc += 32) {
        float4 a0, a1;
        if (rv) { a0 = *(const float4*)(xp + kc); a1 = *(const float4*)(xp + kc + 4); }
        else { a0 = make_float4(0.f,0.f,0.f,0.f); a1 = a0; }
        half8_t af;
        af[0]=(_Float16)a0.x; af[1]=(_Float16)a0.y; af[2]=(_Float16)a0.z; af[3]=(_Float16)a0.w;
        af[4]=(_Float16)a1.x; af[5]=(_Float16)a1.y; af[6]=(_Float16)a1.z; af[7]=(_Float16)a1.w;
        #pragma unroll
        for (int s = 0; s < 8; s++) {
            const _Float16* bp = W1t + (size_t)(s * 16 + lrow) * IN_CH + kc + kgrp * 8;
            half8_t bf = *(const half8_t*)bp;
            acc[s] = __builtin_amdgcn_mfma_f32_16x16x32_f16(af, bf, acc[s], 0, 0, 0);
        }
    }

    // C/D: col = lane&15 (=lrow), row = kgrp*4 + r
    int orow0 = blockIdx.x * 64 + wid * 16 + kgrp * 4;
    #pragma unroll
    for (int r = 0; r < 4; r++) {
        int orow = orow0 + r;
        if (orow < n) {
            float sc = dinv[orow];
            _Float16* po = xwh + ((size_t)orow << 7) + lrow;
            #pragma unroll
            for (int s = 0; s < 8; s++) po[s * 16] = (_Float16)(sc * acc[s][r]);
        }
    }
}

// ---------------- GCN aggregate: wave/node, 16 lanes/edge x half8, fp16 pair-add ----------------
__global__ __launch_bounds__(256) void k_gcn(const _Float16* __restrict__ xwh, const int* __restrict__ csr,
                                             const int* __restrict__ off, const float* __restrict__ dinv,
                                             const float* __restrict__ b1, _Float16* __restrict__ hh, int n) {
    int w = (blockIdx.x * 256 + threadIdx.x) >> 6;
    int lane = threadIdx.x & 63;
    if (w >= n) return;
    int egrp = lane >> 4;          // which of 4 edges this lane serves
    int c8 = (lane & 15) * 8;      // 8 contiguous cols
    float acc[8];
    #pragma unroll
    for (int j = 0; j < 8; j++) acc[j] = 0.f;

    int beg = off[w], end = off[w + 1];
    int i = beg;
    for (; i + 16 <= end; i += 16) {
        int s0 = csr[i + egrp];
        int s1 = csr[i + 4 + egrp];
        int s2 = csr[i + 8 + egrp];
        int s3 = csr[i + 12 + egrp];
        half8_t v0 = *(const half8_t*)(xwh + ((size_t)s0 << 7) + c8);
        half8_t v1 = *(const half8_t*)(xwh + ((size_t)s1 << 7) + c8);
        half8_t v2 = *(const half8_t*)(xwh + ((size_t)s2 << 7) + c8);
        half8_t v3 = *(const half8_t*)(xwh + ((size_t)s3 << 7) + c8);
        half8_t p01 = v0 + v1;          // v_pk_add_f16 (error ~ulp, shrunk by dinv later)
        half8_t p23 = v2 + v3;
        #pragma unroll
        for (int j = 0; j < 8; j++)
            acc[j] += (float)p01[j] + (float)p23[j];
    }
    for (; i + 4 <= end; i += 4) {
        int s = csr[i + egrp];
        half8_t v = *(const half8_t*)(xwh + ((size_t)s << 7) + c8);
        #pragma unroll
        for (int j = 0; j < 8; j++) acc[j] += (float)v[j];
    }
    if (i < end && egrp < (end - i)) {
        int s = csr[i + egrp];
        half8_t v = *(const half8_t*)(xwh + ((size_t)s << 7) + c8);
        #pragma unroll
        for (int j = 0; j < 8; j++) acc[j] += (float)v[j];
    }

    #pragma unroll
    for (int j = 0; j < 8; j++) {
        acc[j] += __shfl_xor(acc[j], 16, 64);
        acc[j] += __shfl_xor(acc[j], 32, 64);
    }
    if (egrp == 0) {
        float di = dinv[w];
        half8_t self = *(const half8_t*)(xwh + ((size_t)w << 7) + c8);
        float4 bb0 = *(const float4*)(b1 + c8);
        float4 bb1 = *(const float4*)(b1 + c8 + 4);
        float bv[8] = {bb0.x, bb0.y, bb0.z, bb0.w, bb1.x, bb1.y, bb1.z, bb1.w};
        half8_t o;
        #pragma unroll
        for (int j = 0; j < 8; j++)
            o[j] = (_Float16)fmaxf(fmaf(di, acc[j] + (float)self[j], bv[j]), 0.f);
        *(half8_t*)(hh + ((size_t)w << 7) + c8) = o;
    }
}

// ---------------- GEMM2 (MFMA): h2h[pad 256] = fp16( h @ W2 )  [N,128]x[128,192] ----------------
__global__ __launch_bounds__(256) void k_gemm2m(const _Float16* __restrict__ hh, const _Float16* __restrict__ W2t,
                                                _Float16* __restrict__ h2h, int n) {
    int wid = threadIdx.x >> 6, lane = threadIdx.x & 63;
    int lrow = lane & 15, kgrp = lane >> 4;
    int arow = blockIdx.x * 64 + wid * 16 + lrow;
    bool rv = arow < n;
    const _Float16* hp = hh + ((size_t)arow << 7) + kgrp * 8;

    float4_t acc[12];
    #pragma unroll
    for (int s = 0; s < 12; s++) acc[s] = (float4_t)(0.f);

    #pragma unroll
    for (int kc = 0; kc < HID; kc += 32) {
        half8_t af = (half8_t)((_Float16)0.f);
        if (rv) af = *(const half8_t*)(hp + kc);
        #pragma unroll
        for (int s = 0; s < 12; s++) {
            const _Float16* bp = W2t + (size_t)(s * 16 + lrow) * HID + kc + kgrp * 8;
            half8_t bf = *(const half8_t*)bp;
            acc[s] = __builtin_amdgcn_mfma_f32_16x16x32_f16(af, bf, acc[s], 0, 0, 0);
        }
    }

    int orow0 = blockIdx.x * 64 + wid * 16 + kgrp * 4;
    #pragma unroll
    for (int r = 0; r < 4; r++) {
        int orow = orow0 + r;
        if (orow < n) {
            _Float16* po = h2h + ((size_t)orow << 8) + lrow;
            #pragma unroll
            for (int s = 0; s < 12; s++) po[s * 16] = (_Float16)acc[s][r];
        }
    }
}

// ---------------- attention scores: 48 lanes cover all 192 cols, 3 heads concurrent ----------------
__global__ __launch_bounds__(256) void k_att(const _Float16* __restrict__ h2h, const float* __restrict__ att_s,
                                             const float* __restrict__ att_d, float* __restrict__ a_s4,
                                             float* __restrict__ a_d4, int n) {
    int w = (blockIdx.x * 256 + threadIdx.x) >> 6;
    int lane = threadIdx.x & 63;
    if (w >= n) return;
    bool act = lane < 48;
    int ll = act ? lane : (lane - 48);
    int hd = ll >> 4;
    int c4 = ll * 4;

    half4_t hv = *(const half4_t*)(h2h + ((size_t)w << 8) + c4);
    float4 as = *(const float4*)(att_s + c4);
    float4 ad = *(const float4*)(att_d + c4);
    float vs = (float)hv[0] * as.x + (float)hv[1] * as.y + (float)hv[2] * as.z + (float)hv[3] * as.w;
    float vd = (float)hv[0] * ad.x + (float)hv[1] * ad.y + (float)hv[2] * ad.z + (float)hv[3] * ad.w;
    #pragma unroll
    for (int o = 1; o < 16; o <<= 1) {
        vs += __shfl_xor(vs, o, 64);
        vd += __shfl_xor(vd, o, 64);
    }
    if (act && (ll & 15) == 0) {
        a_s4[w * 4 + hd] = vs;
        a_d4[w * 4 + hd] = vd;
    }
}

// ---------------- global per-head max of a_s (multi-block + fkey atomicMax) ----------------
__global__ __launch_bounds__(1024) void k_asmax(const float* __restrict__ a_s4, int n, unsigned* __restrict__ asmaxk) {
    int i = blockIdx.x * 1024 + threadIdx.x;
    float m0 = -1e30f, m1 = -1e30f, m2 = -1e30f;
    if (i < n) {
        float4 v = *(const float4*)(a_s4 + (size_t)i * 4);
        m0 = v.x; m1 = v.y; m2 = v.z;
    }
    #pragma unroll
    for (int o = 32; o > 0; o >>= 1) {
        m0 = fmaxf(m0, __shfl_xor(m0, o, 64));
        m1 = fmaxf(m1, __shfl_xor(m1, o, 64));
        m2 = fmaxf(m2, __shfl_xor(m2, o, 64));
    }
    __shared__ float sm[16][3];
    int lane = threadIdx.x & 63, wid = threadIdx.x >> 6;
    if (lane == 0) { sm[wid][0] = m0; sm[wid][1] = m1; sm[wid][2] = m2; }
    __syncthreads();
    if (threadIdx.x == 0) {
        for (int j = 1; j < 16; j++) {
            m0 = fmaxf(m0, sm[j][0]); m1 = fmaxf(m1, sm[j][1]); m2 = fmaxf(m2, sm[j][2]);
        }
        atomicMax(asmaxk + 0, fkey(m0));
        atomicMax(asmaxk + 1, fkey(m1));
        atomicMax(asmaxk + 2, fkey(m2));
    }
}

// ---------------- GAT aggregate: wave/node, inline weights, fma_mix on raw fp16, unroll-4 ----------------
#define GAT_EDGE(ev, hv) do { \
    float wl = __expf(lrelu((ev) + adh) - Ch); \
    ssum += wl; \
    a0 = fmaf(wl, (float)(hv)[0], a0); \
    a1 = fmaf(wl, (float)(hv)[1], a1); \
    a2 = fmaf(wl, (float)(hv)[2], a2); \
    a3 = fmaf(wl, (float)(hv)[3], a3); \
} while (0)

__global__ __launch_bounds__(256) void k_gat(const _Float16* __restrict__ h2h, const int* __restrict__ csr,
                                             const int* __restrict__ off, const float* __restrict__ a_s4,
                                             const float* __restrict__ a_d4, const unsigned* __restrict__ asmaxk,
                                             const float* __restrict__ b2, float* __restrict__ out, int n) {
    int w = (blockIdx.x * 256 + threadIdx.x) >> 6;
    int lane = threadIdx.x & 63;
    if (w >= n) return;
    bool act = lane < 48;
    int ll = act ? lane : (lane - 48);
    int hd = ll >> 4;
    int c4 = ll * 4;

    float adh = a_d4[w * 4 + hd];
    float Ch  = lrelu(fdec(asmaxk[hd]) + adh);
    float ash = a_s4[w * 4 + hd];
    float wsl = __expf(lrelu(ash + adh) - Ch);     // self-loop weight
    float ssum = wsl;
    half4_t hv = *(const half4_t*)(h2h + ((size_t)w << 8) + c4);
    float a0 = wsl * (float)hv[0], a1 = wsl * (float)hv[1];
    float a2 = wsl * (float)hv[2], a3 = wsl * (float)hv[3];

    int beg = off[w], end = off[w + 1];
    int i = beg;
    for (; i + 4 <= end; i += 4) {
        int sA = csr[i], sB = csr[i + 1], sC = csr[i + 2], sD = csr[i + 3];
        float eA = a_s4[(size_t)sA * 4 + hd];
        float eB = a_s4[(size_t)sB * 4 + hd];
        float eC = a_s4[(size_t)sC * 4 + hd];
        float eD = a_s4[(size_t)sD * 4 + hd];
        half4_t hA = *(const half4_t*)(h2h + ((size_t)sA << 8) + c4);
        half4_t hB = *(const half4_t*)(h2h + ((size_t)sB << 8) + c4);
        half4_t hC = *(const half4_t*)(h2h + ((size_t)sC << 8) + c4);
        half4_t hD = *(const half4_t*)(h2h + ((size_t)sD << 8) + c4);
        GAT_EDGE(eA, hA); GAT_EDGE(eB, hB); GAT_EDGE(eC, hC); GAT_EDGE(eD, hD);
    }
    for (; i < end; i++) {
        int s = csr[i];
        float ev = a_s4[(size_t)s * 4 + hd];
        half4_t hx = *(const half4_t*)(h2h + ((size_t)s << 8) + c4);
        GAT_EDGE(ev, hx);
    }

    if (act) {
        float inv = 1.f / ssum;
        float4 bb = *(const float4*)(b2 + c4);
        float4 o;
        o.x = fmaxf(fmaf(a0, inv, bb.x), 0.f);
        o.y = fmaxf(fmaf(a1, inv, bb.y), 0.f);
        o.z = fmaxf(fmaf(a2, inv, bb.z), 0.f);
        o.w = fmaxf(fmaf(a3, inv, bb.w), 0.f);
        *(float4*)(out + (size_t)w * OC + c4) = o;
    }
}

// ---------------- launcher ----------------
extern "C" void kernel_launch(void* const* d_in, const int* in_sizes, int n_in,
                              void* d_out, int out_size, void* d_ws, size_t ws_size,
                              hipStream_t stream) {
    const float* x        = (const float*)d_in[0];
    const int*   ei       = (const int*)d_in[1];
    const float* W1       = (const float*)d_in[2];
    const float* b1       = (const float*)d_in[3];
    const float* W2       = (const float*)d_in[4];
    const float* att_src  = (const float*)d_in[5];
    const float* att_dst  = (const float*)d_in[6];
    const float* b2       = (const float*)d_in[7];
    float* out = (float*)d_out;

    const int n = in_sizes[0] / IN_CH;     // 50000
    const int E = in_sizes[1] / 2;         // 800000
    const int* src = ei;
    const int* dst = ei + E;

    // workspace layout (bytes), 256-aligned
    char* ws = (char*)d_ws;
    int*      bcnt   = (int*)(ws + 0);               // 391 i   (memset 0)
    unsigned* asmaxk = (unsigned*)(ws + 2048);       // 3 u     (memset 0)
    int*      off    = (int*)(ws + 4096);            // 50001 i
    float*    dinv   = (float*)(ws + 204800);        // 50000 f
    int*      bbase  = (int*)(ws + 405504);          // 391 i
    _Float16* W1t    = (_Float16*)(ws + 407552);     // 128*256 h
    _Float16* W2t    = (_Float16*)(ws + 473088);     // 192*128 h
    unsigned* bstage = (unsigned*)(ws + 522240);     // 391*4096 u = 6.4 MB
    int*      csr    = (int*)(ws + 6928384);         // 800000 i
    float*    a_s4   = (float*)(ws + 10128384);      // 50000*4 f
    float*    a_d4   = (float*)(ws + 10928384);      // 50000*4 f
    _Float16* xwh    = (_Float16*)(ws + 11728384);   // 50000*128 h (pre-scaled by dinv)
    _Float16* hh     = (_Float16*)(ws + 24528384);   // 50000*128 h
    _Float16* h2h    = (_Float16*)(ws + 37328384);   // 50000*256 h (rows padded to 512B)
    // total ~63 MB

    (void)hipMemsetAsync(ws, 0, 2064, stream);       // bcnt + asmaxk

    int egrid = (E + 255) / 256;                     // 3125 (covers cvt range 81920 too)
    int nb = (n + 1023) / 1024;                      // 49
    k_bucket<<<egrid, 256, 0, stream>>>(src, dst, E, bcnt, bstage, W1, W2, W1t, W2t);
    k_bscan<<<1, 512, 0, stream>>>(bcnt, bbase, off, NBK, n);
    k_bsort<<<NBK, 256, 0, stream>>>(bstage, bcnt, bbase, off, dinv, csr, n);

    int gm = (n + 63) / 64;    // 782 blocks, 4 waves each
    k_gemm1m<<<gm, 256, 0, stream>>>(x, W1t, dinv, xwh, n);

    int ngrid = (n + 3) / 4;   // 4 waves per block
    k_gcn<<<ngrid, 256, 0, stream>>>(xwh, csr, off, dinv, b1, hh, n);

    k_gemm2m<<<gm, 256, 0, stream>>>(hh, W2t, h2h, n);

    k_att<<<ngrid, 256, 0, stream>>>(h2h, att_src, att_dst, a_s4, a_d4, n);
    k_asmax<<<nb, 1024, 0, stream>>>(a_s4, n, asmaxk);
    k_gat<<<ngrid, 256, 0, stream>>>(h2h, csr, off, a_s4, a_d4, asmaxk, b2, out, n);
}

// Round 13
// 274.371 us; speedup vs baseline: 1.7029x; 1.7029x over previous
//
#include <hip/hip_runtime.h>
#include <hip/hip_fp16.h>
#include <math.h>

// Problem constants (verified against reference setup_inputs)
#define NODES    50000
#define IN_CH    256
#define HID      128
#define HEADS    3
#define HC       64
#define OC       (HEADS*HC)   // 192
#define NEG_SLOPE 0.2f

typedef _Float16 half8_t __attribute__((ext_vector_type(8)));
typedef _Float16 half4_t __attribute__((ext_vector_type(4)));
typedef float float4_t __attribute__((ext_vector_type(4)));

__device__ __forceinline__ float lrelu(float v) { return v > 0.f ? v : NEG_SLOPE * v; }

// monotone unsigned key for float max-atomics (fkey(finite) > 0, so memset-0 is identity)
__device__ __forceinline__ unsigned fkey(float f) {
    unsigned b = __float_as_uint(f);
    return (b & 0x80000000u) ? ~b : (b | 0x80000000u);
}
__device__ __forceinline__ float fdec(unsigned k) {
    unsigned b = (k & 0x80000000u) ? (k ^ 0x80000000u) : ~k;
    return __uint_as_float(b);
}

// ---------------- CSR build (k_hist also does the weight fp16-transpose prepass) ----------------

__global__ __launch_bounds__(256) void k_hist(const int* __restrict__ dst, int E, int* __restrict__ cnt,
                                              const float* __restrict__ W1, const float* __restrict__ W2,
                                              _Float16* __restrict__ W1t, _Float16* __restrict__ W2t) {
    int e = blockIdx.x * 256 + threadIdx.x;
    if (e < E) atomicAdd(&cnt[dst[e]], 1);
    if (e < IN_CH * HID) {
        int c = e >> 8, k = e & 255;                 // W1t[c][k] = W1[k][c]
        W1t[e] = (_Float16)W1[(size_t)k * HID + c];
    } else if (e < IN_CH * HID + HID * OC) {
        int u = e - IN_CH * HID;
        int c = u >> 7, k = u & 127;                 // W2t[c][k] = W2[k][c]
        W2t[u] = (_Float16)W2[(size_t)k * OC + c];
    }
}

__global__ __launch_bounds__(1024) void k_scanA(const int* __restrict__ cnt, int* __restrict__ off,
                                                float* __restrict__ dinv, int* __restrict__ bsum, int n) {
    __shared__ int wsums[16];
    int tid = threadIdx.x, lane = tid & 63, wid = tid >> 6;
    int i = blockIdx.x * 1024 + tid;
    int v = (i < n) ? cnt[i] : 0;
    int incl = v;
    #pragma unroll
    for (int d = 1; d < 64; d <<= 1) {
        int t = __shfl_up(incl, d, 64);
        if (lane >= d) incl += t;
    }
    if (lane == 63) wsums[wid] = incl;
    __syncthreads();
    if (tid == 0) {
        int run = 0;
        #pragma unroll
        for (int j = 0; j < 16; j++) { int t = wsums[j]; wsums[j] = run; run += t; }
        bsum[blockIdx.x] = run;
    }
    __syncthreads();
    if (i < n) {
        off[i] = wsums[wid] + incl - v;
        dinv[i] = rsqrtf((float)(v + 1));   // +1 for self loop
    }
}

__global__ __launch_bounds__(64) void k_scanB(const int* __restrict__ bsum, int* __restrict__ bbase,
                                              int* __restrict__ off, int nb, int n) {
    int tid = threadIdx.x;
    int v = (tid < nb) ? bsum[tid] : 0;
    int incl = v;
    #pragma unroll
    for (int d = 1; d < 64; d <<= 1) {
        int t = __shfl_up(incl, d, 64);
        if (tid >= d) incl += t;
    }
    bbase[tid] = incl - v;
    if (tid == 63) off[n] = incl;   // grand total = E
}

__global__ __launch_bounds__(256) void k_scanC(int* __restrict__ off, const int* __restrict__ bbase, int n) {
    int i = blockIdx.x * 256 + threadIdx.x;
    if (i < n) off[i] += bbase[i >> 10];
}

__global__ __launch_bounds__(256) void k_fill(const int* __restrict__ src, const int* __restrict__ dst, int E,
                                              const int* __restrict__ off, int* __restrict__ fill,
                                              int* __restrict__ csr) {
    int e = blockIdx.x * 256 + threadIdx.x;
    if (e < E) {
        int d = dst[e];
        int p = off[d] + atomicAdd(&fill[d], 1);
        csr[p] = src[e];
    }
}

// ---------------- GEMM1 (MFMA): xwh = fp16( dinv[row] * (x @ W1) ) ----------------
__global__ __launch_bounds__(256) void k_gemm1m(const float* __restrict__ x, const _Float16* __restrict__ W1t,
                                                const float* __restrict__ dinv,
                                                _Float16* __restrict__ xwh, int n) {
    int wid = threadIdx.x >> 6, lane = threadIdx.x & 63;
    int lrow = lane & 15, kgrp = lane >> 4;          // A: row=lrow, k-chunk=kgrp*8
    int arow = blockIdx.x * 64 + wid * 16 + lrow;
    bool rv = arow < n;
    const float* xp = x + (size_t)arow * IN_CH + kgrp * 8;

    float4_t acc[8];
    #pragma unroll
    for (int s = 0; s < 8; s++) acc[s] = (float4_t)(0.f);

    #pragma unroll
    for (int kc = 0; kc < IN_CH; kc += 32) {
        float4 a0, a1;
        if (rv) { a0 = *(const float4*)(xp + kc); a1 = *(const float4*)(xp + kc + 4); }
        else { a0 = make_float4(0.f,0.f,0.f,0.f); a1 = a0; }
        half8_t af;
        af[0]=(_Float16)a0.x; af[1]=(_Float16)a0.y; af[2]=(_Float16)a0.z; af[3]=(_Float16)a0.w;
        af[4]=(_Float16)a1.x; af[5]=(_Float16)a1.y; af[6]=(_Float16)a1.z; af[7]=(_Float16)a1.w;
        #pragma unroll
        for (int s = 0; s < 8; s++) {
            const _Float16* bp = W1t + (size_t)(s * 16 + lrow) * IN_CH + kc + kgrp * 8;
            half8_t bf = *(const half8_t*)bp;
            acc[s] = __builtin_amdgcn_mfma_f32_16x16x32_f16(af, bf, acc[s], 0, 0, 0);
        }
    }

    // C/D: col = lane&15 (=lrow), row = kgrp*4 + r
    int orow0 = blockIdx.x * 64 + wid * 16 + kgrp * 4;
    #pragma unroll
    for (int r = 0; r < 4; r++) {
        int orow = orow0 + r;
        if (orow < n) {
            float sc = dinv[orow];
            _Float16* po = xwh + ((size_t)orow << 7) + lrow;
            #pragma unroll
            for (int s = 0; s < 8; s++) po[s * 16] = (_Float16)(sc * acc[s][r]);
        }
    }
}

// ---------------- FUSED: GCN aggregate (-> LDS tile) + GEMM2 (MFMA from LDS) ----------------
// Block = 512 threads (8 waves), owns 64 nodes. Phase 1: wave w aggregates nodes w*8..w*8+7
// into a swizzled LDS tile (chunk ^= row&7 kills the 256B-stride bank conflict).
// Phase 2: 4 row-tiles x 2 col-halves of the 64x192 GEMM, A-frags from LDS, B from W2t (L2-hot).
#define HSW(row, chunk) ((((chunk) ^ ((row) & 7)) << 3))

__global__ __launch_bounds__(512) void k_gcn2(const _Float16* __restrict__ xwh, const int* __restrict__ csr,
                                              const int* __restrict__ off, const float* __restrict__ dinv,
                                              const float* __restrict__ b1, const _Float16* __restrict__ W2t,
                                              _Float16* __restrict__ h2h, int n) {
    __shared__ _Float16 hs[64][128];   // 16 KB
    int w8 = threadIdx.x >> 6;         // wave 0..7
    int lane = threadIdx.x & 63;
    int egrp = lane >> 4;              // which of 4 edges this lane serves
    int chunk = lane & 15;             // 8-elem chunk this lane owns
    int c8 = chunk * 8;
    int base = blockIdx.x * 64;

    // ---- phase 1: aggregate 8 nodes per wave ----
    for (int j = 0; j < 8; j++) {
        int ndl = w8 * 8 + j;
        int nd = base + ndl;
        if (nd >= n) {
            if (egrp == 0) *(half8_t*)&hs[ndl][HSW(ndl, chunk)] = (half8_t)((_Float16)0.f);
            continue;
        }
        float acc[8];
        #pragma unroll
        for (int q = 0; q < 8; q++) acc[q] = 0.f;

        int beg = off[nd], end = off[nd + 1];
        int i = beg;
        for (; i + 16 <= end; i += 16) {
            int s0 = csr[i + egrp];
            int s1 = csr[i + 4 + egrp];
            int s2 = csr[i + 8 + egrp];
            int s3 = csr[i + 12 + egrp];
            half8_t v0 = *(const half8_t*)(xwh + ((size_t)s0 << 7) + c8);
            half8_t v1 = *(const half8_t*)(xwh + ((size_t)s1 << 7) + c8);
            half8_t v2 = *(const half8_t*)(xwh + ((size_t)s2 << 7) + c8);
            half8_t v3 = *(const half8_t*)(xwh + ((size_t)s3 << 7) + c8);
            half8_t p01 = v0 + v1;      // v_pk_add_f16 (ulp error, shrunk by dinv later)
            half8_t p23 = v2 + v3;
            #pragma unroll
            for (int q = 0; q < 8; q++)
                acc[q] += (float)p01[q] + (float)p23[q];
        }
        for (; i + 4 <= end; i += 4) {
            int s = csr[i + egrp];
            half8_t v = *(const half8_t*)(xwh + ((size_t)s << 7) + c8);
            #pragma unroll
            for (int q = 0; q < 8; q++) acc[q] += (float)v[q];
        }
        if (i < end && egrp < (end - i)) {
            int s = csr[i + egrp];
            half8_t v = *(const half8_t*)(xwh + ((size_t)s << 7) + c8);
            #pragma unroll
            for (int q = 0; q < 8; q++) acc[q] += (float)v[q];
        }

        #pragma unroll
        for (int q = 0; q < 8; q++) {
            acc[q] += __shfl_xor(acc[q], 16, 64);
            acc[q] += __shfl_xor(acc[q], 32, 64);
        }
        if (egrp == 0) {
            float di = dinv[nd];
            half8_t self = *(const half8_t*)(xwh + ((size_t)nd << 7) + c8);
            float4 bb0 = *(const float4*)(b1 + c8);
            float4 bb1 = *(const float4*)(b1 + c8 + 4);
            float bv[8] = {bb0.x, bb0.y, bb0.z, bb0.w, bb1.x, bb1.y, bb1.z, bb1.w};
            half8_t o;
            #pragma unroll
            for (int q = 0; q < 8; q++)
                o[q] = (_Float16)fmaxf(fmaf(di, acc[q] + (float)self[q], bv[q]), 0.f);
            *(half8_t*)&hs[ndl][HSW(ndl, chunk)] = o;
        }
    }
    __syncthreads();

    // ---- phase 2: GEMM2 64x192 = hs(64x128) @ W2t, 8 waves = 4 row-tiles x 2 col-halves ----
    int rt = w8 >> 1;                  // row tile 0..3
    int ch = w8 & 1;                   // col half 0..1 (subtiles ch*6 .. ch*6+5)
    int lrow = lane & 15, kgrp = lane >> 4;
    int arow_l = rt * 16 + lrow;

    float4_t acc2[6];
    #pragma unroll
    for (int s = 0; s < 6; s++) acc2[s] = (float4_t)(0.f);

    #pragma unroll
    for (int kc = 0; kc < HID; kc += 32) {
        half8_t af = *(const half8_t*)&hs[arow_l][HSW(arow_l, (kc >> 3) + kgrp)];
        #pragma unroll
        for (int s = 0; s < 6; s++) {
            int st = ch * 6 + s;
            const _Float16* bp = W2t + (size_t)(st * 16 + lrow) * HID + kc + kgrp * 8;
            half8_t bf = *(const half8_t*)bp;
            acc2[s] = __builtin_amdgcn_mfma_f32_16x16x32_f16(af, bf, acc2[s], 0, 0, 0);
        }
    }

    int orow0 = base + rt * 16 + kgrp * 4;
    #pragma unroll
    for (int r = 0; r < 4; r++) {
        int orow = orow0 + r;
        if (orow < n) {
            _Float16* po = h2h + ((size_t)orow << 8) + ch * 96 + lrow;
            #pragma unroll
            for (int s = 0; s < 6; s++) po[s * 16] = (_Float16)acc2[s][r];
        }
    }
}

// ---------------- attention scores: 48 lanes cover all 192 cols, 3 heads concurrent ----------------
__global__ __launch_bounds__(256) void k_att(const _Float16* __restrict__ h2h, const float* __restrict__ att_s,
                                             const float* __restrict__ att_d, float* __restrict__ a_s4,
                                             float* __restrict__ a_d4, int n) {
    int w = (blockIdx.x * 256 + threadIdx.x) >> 6;
    int lane = threadIdx.x & 63;
    if (w >= n) return;
    bool act = lane < 48;
    int ll = act ? lane : (lane - 48);
    int hd = ll >> 4;
    int c4 = ll * 4;

    half4_t hv = *(const half4_t*)(h2h + ((size_t)w << 8) + c4);
    float4 as = *(const float4*)(att_s + c4);
    float4 ad = *(const float4*)(att_d + c4);
    float vs = (float)hv[0] * as.x + (float)hv[1] * as.y + (float)hv[2] * as.z + (float)hv[3] * as.w;
    float vd = (float)hv[0] * ad.x + (float)hv[1] * ad.y + (float)hv[2] * ad.z + (float)hv[3] * ad.w;
    #pragma unroll
    for (int o = 1; o < 16; o <<= 1) {
        vs += __shfl_xor(vs, o, 64);
        vd += __shfl_xor(vd, o, 64);
    }
    if (act && (ll & 15) == 0) {
        a_s4[w * 4 + hd] = vs;
        a_d4[w * 4 + hd] = vd;
    }
}

// ---------------- global per-head max of a_s (multi-block + fkey atomicMax) ----------------
__global__ __launch_bounds__(1024) void k_asmax(const float* __restrict__ a_s4, int n, unsigned* __restrict__ asmaxk) {
    int i = blockIdx.x * 1024 + threadIdx.x;
    float m0 = -1e30f, m1 = -1e30f, m2 = -1e30f;
    if (i < n) {
        float4 v = *(const float4*)(a_s4 + (size_t)i * 4);
        m0 = v.x; m1 = v.y; m2 = v.z;
    }
    #pragma unroll
    for (int o = 32; o > 0; o >>= 1) {
        m0 = fmaxf(m0, __shfl_xor(m0, o, 64));
        m1 = fmaxf(m1, __shfl_xor(m1, o, 64));
        m2 = fmaxf(m2, __shfl_xor(m2, o, 64));
    }
    __shared__ float sm[16][3];
    int lane = threadIdx.x & 63, wid = threadIdx.x >> 6;
    if (lane == 0) { sm[wid][0] = m0; sm[wid][1] = m1; sm[wid][2] = m2; }
    __syncthreads();
    if (threadIdx.x == 0) {
        for (int j = 1; j < 16; j++) {
            m0 = fmaxf(m0, sm[j][0]); m1 = fmaxf(m1, sm[j][1]); m2 = fmaxf(m2, sm[j][2]);
        }
        atomicMax(asmaxk + 0, fkey(m0));
        atomicMax(asmaxk + 1, fkey(m1));
        atomicMax(asmaxk + 2, fkey(m2));
    }
}

// ---------------- GAT aggregate: wave/node, inline weights, fma_mix on raw fp16, unroll-4 ----------------
#define GAT_EDGE(ev, hv) do { \
    float wl = __expf(lrelu((ev) + adh) - Ch); \
    ssum += wl; \
    a0 = fmaf(wl, (float)(hv)[0], a0); \
    a1 = fmaf(wl, (float)(hv)[1], a1); \
    a2 = fmaf(wl, (float)(hv)[2], a2); \
    a3 = fmaf(wl, (float)(hv)[3], a3); \
} while (0)

__global__ __launch_bounds__(256) void k_gat(const _Float16* __restrict__ h2h, const int* __restrict__ csr,
                                             const int* __restrict__ off, const float* __restrict__ a_s4,
                                             const float* __restrict__ a_d4, const unsigned* __restrict__ asmaxk,
                                             const float* __restrict__ b2, float* __restrict__ out, int n) {
    int w = (blockIdx.x * 256 + threadIdx.x) >> 6;
    int lane = threadIdx.x & 63;
    if (w >= n) return;
    bool act = lane < 48;
    int ll = act ? lane : (lane - 48);
    int hd = ll >> 4;
    int c4 = ll * 4;

    float adh = a_d4[w * 4 + hd];
    float Ch  = lrelu(fdec(asmaxk[hd]) + adh);
    float ash = a_s4[w * 4 + hd];
    float wsl = __expf(lrelu(ash + adh) - Ch);     // self-loop weight
    float ssum = wsl;
    half4_t hv = *(const half4_t*)(h2h + ((size_t)w << 8) + c4);
    float a0 = wsl * (float)hv[0], a1 = wsl * (float)hv[1];
    float a2 = wsl * (float)hv[2], a3 = wsl * (float)hv[3];

    int beg = off[w], end = off[w + 1];
    int i = beg;
    for (; i + 4 <= end; i += 4) {
        int sA = csr[i], sB = csr[i + 1], sC = csr[i + 2], sD = csr[i + 3];
        float eA = a_s4[(size_t)sA * 4 + hd];
        float eB = a_s4[(size_t)sB * 4 + hd];
        float eC = a_s4[(size_t)sC * 4 + hd];
        float eD = a_s4[(size_t)sD * 4 + hd];
        half4_t hA = *(const half4_t*)(h2h + ((size_t)sA << 8) + c4);
        half4_t hB = *(const half4_t*)(h2h + ((size_t)sB << 8) + c4);
        half4_t hC = *(const half4_t*)(h2h + ((size_t)sC << 8) + c4);
        half4_t hD = *(const half4_t*)(h2h + ((size_t)sD << 8) + c4);
        GAT_EDGE(eA, hA); GAT_EDGE(eB, hB); GAT_EDGE(eC, hC); GAT_EDGE(eD, hD);
    }
    for (; i < end; i++) {
        int s = csr[i];
        float ev = a_s4[(size_t)s * 4 + hd];
        half4_t hx = *(const half4_t*)(h2h + ((size_t)s << 8) + c4);
        GAT_EDGE(ev, hx);
    }

    if (act) {
        float inv = 1.f / ssum;
        float4 bb = *(const float4*)(b2 + c4);
        float4 o;
        o.x = fmaxf(fmaf(a0, inv, bb.x), 0.f);
        o.y = fmaxf(fmaf(a1, inv, bb.y), 0.f);
        o.z = fmaxf(fmaf(a2, inv, bb.z), 0.f);
        o.w = fmaxf(fmaf(a3, inv, bb.w), 0.f);
        *(float4*)(out + (size_t)w * OC + c4) = o;
    }
}

// ---------------- launcher ----------------
extern "C" void kernel_launch(void* const* d_in, const int* in_sizes, int n_in,
                              void* d_out, int out_size, void* d_ws, size_t ws_size,
                              hipStream_t stream) {
    const float* x        = (const float*)d_in[0];
    const int*   ei       = (const int*)d_in[1];
    const float* W1       = (const float*)d_in[2];
    const float* b1       = (const float*)d_in[3];
    const float* W2       = (const float*)d_in[4];
    const float* att_src  = (const float*)d_in[5];
    const float* att_dst  = (const float*)d_in[6];
    const float* b2       = (const float*)d_in[7];
    float* out = (float*)d_out;

    const int n = in_sizes[0] / IN_CH;     // 50000
    const int E = in_sizes[1] / 2;         // 800000
    const int* src = ei;
    const int* dst = ei + E;

    // workspace layout (bytes), 256-aligned
    char* ws = (char*)d_ws;
    int*      cnt    = (int*)(ws + 0);               // 50000 i   (memset 0)
    int*      fill   = (int*)(ws + 200704);          // 50000 i   (memset 0)
    unsigned* asmaxk = (unsigned*)(ws + 401408);     // 3 u       (memset 0)
    int*      off    = (int*)(ws + 401664);          // 50001 i
    float*    dinv   = (float*)(ws + 602368);        // 50000 f
    int*      bsum   = (int*)(ws + 803072);          // 49 i
    int*      bbase  = (int*)(ws + 803328);          // 64 i
    _Float16* W1t    = (_Float16*)(ws + 803584);     // 128*256 h
    _Float16* W2t    = (_Float16*)(ws + 869120);     // 192*128 h
    int*      csr    = (int*)(ws + 918528);          // 800000 i
    float*    a_s4   = (float*)(ws + 4118528);       // 50000*4 f
    float*    a_d4   = (float*)(ws + 4918528);       // 50000*4 f
    _Float16* xwh    = (_Float16*)(ws + 5718528);    // 50000*128 h (pre-scaled by dinv)
    _Float16* h2h    = (_Float16*)(ws + 18518528);   // 50000*256 h (rows padded to 512B)
    // total ~44 MB

    (void)hipMemsetAsync(ws, 0, 401424, stream);     // cnt + fill + asmaxk

    int egrid = (E + 255) / 256;                     // 3125 (covers cvt range 81920 too)
    int nb = (n + 1023) / 1024;                      // 49
    k_hist<<<egrid, 256, 0, stream>>>(dst, E, cnt, W1, W2, W1t, W2t);
    k_scanA<<<nb, 1024, 0, stream>>>(cnt, off, dinv, bsum, n);
    k_scanB<<<1, 64, 0, stream>>>(bsum, bbase, off, nb, n);
    k_scanC<<<(n + 255) / 256, 256, 0, stream>>>(off, bbase, n);
    k_fill<<<egrid, 256, 0, stream>>>(src, dst, E, off, fill, csr);

    int gm = (n + 63) / 64;    // 782 blocks
    k_gemm1m<<<gm, 256, 0, stream>>>(x, W1t, dinv, xwh, n);

    k_gcn2<<<gm, 512, 0, stream>>>(xwh, csr, off, dinv, b1, W2t, h2h, n);

    int ngrid = (n + 3) / 4;   // 4 waves per block
    k_att<<<ngrid, 256, 0, stream>>>(h2h, att_src, att_dst, a_s4, a_d4, n);
    k_asmax<<<nb, 1024, 0, stream>>>(a_s4, n, asmaxk);
    k_gat<<<ngrid, 256, 0, stream>>>(h2h, csr, off, a_s4, a_d4, asmaxk, b2, out, n);
}

// Round 14
// 251.644 us; speedup vs baseline: 1.8567x; 1.0903x over previous
//
#include <hip/hip_runtime.h>
#include <hip/hip_fp16.h>
#include <math.h>

// Problem constants (verified against reference setup_inputs)
#define NODES    50000
#define IN_CH    256
#define HID      128
#define HEADS    3
#define HC       64
#define OC       (HEADS*HC)   // 192
#define NEG_SLOPE 0.2f

typedef _Float16 half8_t __attribute__((ext_vector_type(8)));
typedef _Float16 half4_t __attribute__((ext_vector_type(4)));
typedef float float4_t __attribute__((ext_vector_type(4)));

__device__ __forceinline__ float lrelu(float v) { return v > 0.f ? v : NEG_SLOPE * v; }

// monotone unsigned key for float max-atomics (fkey(finite) > 0, so memset-0 is identity)
__device__ __forceinline__ unsigned fkey(float f) {
    unsigned b = __float_as_uint(f);
    return (b & 0x80000000u) ? ~b : (b | 0x80000000u);
}
__device__ __forceinline__ float fdec(unsigned k) {
    unsigned b = (k & 0x80000000u) ? (k ^ 0x80000000u) : ~k;
    return __uint_as_float(b);
}

// ---------------- CSR build (k_hist also does the weight fp16-transpose prepass) ----------------

__global__ __launch_bounds__(256) void k_hist(const int* __restrict__ dst, int E, int* __restrict__ cnt,
                                              const float* __restrict__ W1, const float* __restrict__ W2,
                                              _Float16* __restrict__ W1t, _Float16* __restrict__ W2t) {
    int e = blockIdx.x * 256 + threadIdx.x;
    if (e < E) atomicAdd(&cnt[dst[e]], 1);
    if (e < IN_CH * HID) {
        int c = e >> 8, k = e & 255;                 // W1t[c][k] = W1[k][c]
        W1t[e] = (_Float16)W1[(size_t)k * HID + c];
    } else if (e < IN_CH * HID + HID * OC) {
        int u = e - IN_CH * HID;
        int c = u >> 7, k = u & 127;                 // W2t[c][k] = W2[k][c]
        W2t[u] = (_Float16)W2[(size_t)k * OC + c];
    }
}

__global__ __launch_bounds__(1024) void k_scanA(const int* __restrict__ cnt, int* __restrict__ off,
                                                float* __restrict__ dinv, int* __restrict__ bsum, int n) {
    __shared__ int wsums[16];
    int tid = threadIdx.x, lane = tid & 63, wid = tid >> 6;
    int i = blockIdx.x * 1024 + tid;
    int v = (i < n) ? cnt[i] : 0;
    int incl = v;
    #pragma unroll
    for (int d = 1; d < 64; d <<= 1) {
        int t = __shfl_up(incl, d, 64);
        if (lane >= d) incl += t;
    }
    if (lane == 63) wsums[wid] = incl;
    __syncthreads();
    if (tid == 0) {
        int run = 0;
        #pragma unroll
        for (int j = 0; j < 16; j++) { int t = wsums[j]; wsums[j] = run; run += t; }
        bsum[blockIdx.x] = run;
    }
    __syncthreads();
    if (i < n) {
        off[i] = wsums[wid] + incl - v;
        dinv[i] = rsqrtf((float)(v + 1));   // +1 for self loop
    }
}

__global__ __launch_bounds__(64) void k_scanB(const int* __restrict__ bsum, int* __restrict__ bbase,
                                              int* __restrict__ off, int nb, int n) {
    int tid = threadIdx.x;
    int v = (tid < nb) ? bsum[tid] : 0;
    int incl = v;
    #pragma unroll
    for (int d = 1; d < 64; d <<= 1) {
        int t = __shfl_up(incl, d, 64);
        if (tid >= d) incl += t;
    }
    bbase[tid] = incl - v;
    if (tid == 63) off[n] = incl;   // grand total = E
}

__global__ __launch_bounds__(256) void k_scanC(int* __restrict__ off, const int* __restrict__ bbase, int n) {
    int i = blockIdx.x * 256 + threadIdx.x;
    if (i < n) off[i] += bbase[i >> 10];
}

// ---------------- MERGED: k_fill (blocks [0, fillBlocks)) + GEMM1 (blocks [fillBlocks, ...)) ----
// fill: atomic-latency bound, leaves VALU/BW idle; gemm1: MFMA/BW dense; independent -> co-schedule.
__global__ __launch_bounds__(256) void k_fillg1(const int* __restrict__ src, const int* __restrict__ dst, int E,
                                                const int* __restrict__ off, int* __restrict__ fill,
                                                unsigned short* __restrict__ csr,
                                                const float* __restrict__ x, const _Float16* __restrict__ W1t,
                                                const float* __restrict__ dinv, _Float16* __restrict__ xwh,
                                                int n, int fillBlocks) {
    if ((int)blockIdx.x < fillBlocks) {
        int e = blockIdx.x * 256 + threadIdx.x;
        if (e < E) {
            int d = dst[e];
            int p = off[d] + atomicAdd(&fill[d], 1);
            csr[p] = (unsigned short)src[e];
        }
        return;
    }

    // ---- GEMM1 (MFMA): xwh = fp16( dinv[row] * (x @ W1) ) ----
    int bid = blockIdx.x - fillBlocks;
    int wid = threadIdx.x >> 6, lane = threadIdx.x & 63;
    int lrow = lane & 15, kgrp = lane >> 4;          // A: row=lrow, k-chunk=kgrp*8
    int arow = bid * 64 + wid * 16 + lrow;
    bool rv = arow < n;
    const float* xp = x + (size_t)arow * IN_CH + kgrp * 8;

    float4_t acc[8];
    #pragma unroll
    for (int s = 0; s < 8; s++) acc[s] = (float4_t)(0.f);

    #pragma unroll
    for (int kc = 0; kc < IN_CH; kc += 32) {
        float4 a0, a1;
        if (rv) { a0 = *(const float4*)(xp + kc); a1 = *(const float4*)(xp + kc + 4); }
        else { a0 = make_float4(0.f,0.f,0.f,0.f); a1 = a0; }
        half8_t af;
        af[0]=(_Float16)a0.x; af[1]=(_Float16)a0.y; af[2]=(_Float16)a0.z; af[3]=(_Float16)a0.w;
        af[4]=(_Float16)a1.x; af[5]=(_Float16)a1.y; af[6]=(_Float16)a1.z; af[7]=(_Float16)a1.w;
        #pragma unroll
        for (int s = 0; s < 8; s++) {
            const _Float16* bp = W1t + (size_t)(s * 16 + lrow) * IN_CH + kc + kgrp * 8;
            half8_t bf = *(const half8_t*)bp;
            acc[s] = __builtin_amdgcn_mfma_f32_16x16x32_f16(af, bf, acc[s], 0, 0, 0);
        }
    }

    // C/D: col = lane&15 (=lrow), row = kgrp*4 + r
    int orow0 = bid * 64 + wid * 16 + kgrp * 4;
    #pragma unroll
    for (int r = 0; r < 4; r++) {
        int orow = orow0 + r;
        if (orow < n) {
            float sc = dinv[orow];
            _Float16* po = xwh + ((size_t)orow << 7) + lrow;
            #pragma unroll
            for (int s = 0; s < 8; s++) po[s * 16] = (_Float16)(sc * acc[s][r]);
        }
    }
}

// ---------------- GCN aggregate: wave/node, 16 lanes/edge x half8, fp16 pair-add ----------------
__global__ __launch_bounds__(256) void k_gcn(const _Float16* __restrict__ xwh, const unsigned short* __restrict__ csr,
                                             const int* __restrict__ off, const float* __restrict__ dinv,
                                             const float* __restrict__ b1, _Float16* __restrict__ hh, int n) {
    int w = (blockIdx.x * 256 + threadIdx.x) >> 6;
    int lane = threadIdx.x & 63;
    if (w >= n) return;
    int egrp = lane >> 4;          // which of 4 edges this lane serves
    int c8 = (lane & 15) * 8;      // 8 contiguous cols
    float acc[8];
    #pragma unroll
    for (int j = 0; j < 8; j++) acc[j] = 0.f;

    int beg = off[w], end = off[w + 1];
    int i = beg;
    for (; i + 16 <= end; i += 16) {
        int s0 = csr[i + egrp];
        int s1 = csr[i + 4 + egrp];
        int s2 = csr[i + 8 + egrp];
        int s3 = csr[i + 12 + egrp];
        half8_t v0 = *(const half8_t*)(xwh + ((size_t)s0 << 7) + c8);
        half8_t v1 = *(const half8_t*)(xwh + ((size_t)s1 << 7) + c8);
        half8_t v2 = *(const half8_t*)(xwh + ((size_t)s2 << 7) + c8);
        half8_t v3 = *(const half8_t*)(xwh + ((size_t)s3 << 7) + c8);
        half8_t p01 = v0 + v1;          // v_pk_add_f16 (error ~ulp, shrunk by dinv later)
        half8_t p23 = v2 + v3;
        #pragma unroll
        for (int j = 0; j < 8; j++)
            acc[j] += (float)p01[j] + (float)p23[j];
    }
    for (; i + 4 <= end; i += 4) {
        int s = csr[i + egrp];
        half8_t v = *(const half8_t*)(xwh + ((size_t)s << 7) + c8);
        #pragma unroll
        for (int j = 0; j < 8; j++) acc[j] += (float)v[j];
    }
    if (i < end && egrp < (end - i)) {
        int s = csr[i + egrp];
        half8_t v = *(const half8_t*)(xwh + ((size_t)s << 7) + c8);
        #pragma unroll
        for (int j = 0; j < 8; j++) acc[j] += (float)v[j];
    }

    #pragma unroll
    for (int j = 0; j < 8; j++) {
        acc[j] += __shfl_xor(acc[j], 16, 64);
        acc[j] += __shfl_xor(acc[j], 32, 64);
    }
    if (egrp == 0) {
        float di = dinv[w];
        half8_t self = *(const half8_t*)(xwh + ((size_t)w << 7) + c8);
        float4 bb0 = *(const float4*)(b1 + c8);
        float4 bb1 = *(const float4*)(b1 + c8 + 4);
        float bv[8] = {bb0.x, bb0.y, bb0.z, bb0.w, bb1.x, bb1.y, bb1.z, bb1.w};
        half8_t o;
        #pragma unroll
        for (int j = 0; j < 8; j++)
            o[j] = (_Float16)fmaxf(fmaf(di, acc[j] + (float)self[j], bv[j]), 0.f);
        *(half8_t*)(hh + ((size_t)w << 7) + c8) = o;
    }
}

// ---------------- GEMM2 (MFMA): h2h[pad 256] = fp16( h @ W2 )  [N,128]x[128,192] ----------------
__global__ __launch_bounds__(256) void k_gemm2m(const _Float16* __restrict__ hh, const _Float16* __restrict__ W2t,
                                                _Float16* __restrict__ h2h, int n) {
    int wid = threadIdx.x >> 6, lane = threadIdx.x & 63;
    int lrow = lane & 15, kgrp = lane >> 4;
    int arow = blockIdx.x * 64 + wid * 16 + lrow;
    bool rv = arow < n;
    const _Float16* hp = hh + ((size_t)arow << 7) + kgrp * 8;

    float4_t acc[12];
    #pragma unroll
    for (int s = 0; s < 12; s++) acc[s] = (float4_t)(0.f);

    #pragma unroll
    for (int kc = 0; kc < HID; kc += 32) {
        half8_t af = (half8_t)((_Float16)0.f);
        if (rv) af = *(const half8_t*)(hp + kc);
        #pragma unroll
        for (int s = 0; s < 12; s++) {
            const _Float16* bp = W2t + (size_t)(s * 16 + lrow) * HID + kc + kgrp * 8;
            half8_t bf = *(const half8_t*)bp;
            acc[s] = __builtin_amdgcn_mfma_f32_16x16x32_f16(af, bf, acc[s], 0, 0, 0);
        }
    }

    int orow0 = blockIdx.x * 64 + wid * 16 + kgrp * 4;
    #pragma unroll
    for (int r = 0; r < 4; r++) {
        int orow = orow0 + r;
        if (orow < n) {
            _Float16* po = h2h + ((size_t)orow << 8) + lrow;
            #pragma unroll
            for (int s = 0; s < 12; s++) po[s * 16] = (_Float16)acc[s][r];
        }
    }
}

// ---------------- attention scores: 48 lanes cover all 192 cols, 3 heads concurrent ----------------
__global__ __launch_bounds__(256) void k_att(const _Float16* __restrict__ h2h, const float* __restrict__ att_s,
                                             const float* __restrict__ att_d, float* __restrict__ a_s4,
                                             float* __restrict__ a_d4, int n) {
    int w = (blockIdx.x * 256 + threadIdx.x) >> 6;
    int lane = threadIdx.x & 63;
    if (w >= n) return;
    bool act = lane < 48;
    int ll = act ? lane : (lane - 48);
    int hd = ll >> 4;
    int c4 = ll * 4;

    half4_t hv = *(const half4_t*)(h2h + ((size_t)w << 8) + c4);
    float4 as = *(const float4*)(att_s + c4);
    float4 ad = *(const float4*)(att_d + c4);
    float vs = (float)hv[0] * as.x + (float)hv[1] * as.y + (float)hv[2] * as.z + (float)hv[3] * as.w;
    float vd = (float)hv[0] * ad.x + (float)hv[1] * ad.y + (float)hv[2] * ad.z + (float)hv[3] * ad.w;
    #pragma unroll
    for (int o = 1; o < 16; o <<= 1) {
        vs += __shfl_xor(vs, o, 64);
        vd += __shfl_xor(vd, o, 64);
    }
    if (act && (ll & 15) == 0) {
        a_s4[w * 4 + hd] = vs;
        a_d4[w * 4 + hd] = vd;
    }
}

// ---------------- global per-head max of a_s (multi-block + fkey atomicMax) ----------------
__global__ __launch_bounds__(1024) void k_asmax(const float* __restrict__ a_s4, int n, unsigned* __restrict__ asmaxk) {
    int i = blockIdx.x * 1024 + threadIdx.x;
    float m0 = -1e30f, m1 = -1e30f, m2 = -1e30f;
    if (i < n) {
        float4 v = *(const float4*)(a_s4 + (size_t)i * 4);
        m0 = v.x; m1 = v.y; m2 = v.z;
    }
    #pragma unroll
    for (int o = 32; o > 0; o >>= 1) {
        m0 = fmaxf(m0, __shfl_xor(m0, o, 64));
        m1 = fmaxf(m1, __shfl_xor(m1, o, 64));
        m2 = fmaxf(m2, __shfl_xor(m2, o, 64));
    }
    __shared__ float sm[16][3];
    int lane = threadIdx.x & 63, wid = threadIdx.x >> 6;
    if (lane == 0) { sm[wid][0] = m0; sm[wid][1] = m1; sm[wid][2] = m2; }
    __syncthreads();
    if (threadIdx.x == 0) {
        for (int j = 1; j < 16; j++) {
            m0 = fmaxf(m0, sm[j][0]); m1 = fmaxf(m1, sm[j][1]); m2 = fmaxf(m2, sm[j][2]);
        }
        atomicMax(asmaxk + 0, fkey(m0));
        atomicMax(asmaxk + 1, fkey(m1));
        atomicMax(asmaxk + 2, fkey(m2));
    }
}

// ---------------- GAT aggregate: wave/node, inline weights, fma_mix on raw fp16, unroll-4 ----------------
#define GAT_EDGE(ev, hv) do { \
    float wl = __expf(lrelu((ev) + adh) - Ch); \
    ssum += wl; \
    a0 = fmaf(wl, (float)(hv)[0], a0); \
    a1 = fmaf(wl, (float)(hv)[1], a1); \
    a2 = fmaf(wl, (float)(hv)[2], a2); \
    a3 = fmaf(wl, (float)(hv)[3], a3); \
} while (0)

__global__ __launch_bounds__(256) void k_gat(const _Float16* __restrict__ h2h, const unsigned short* __restrict__ csr,
                                             const int* __restrict__ off, const float* __restrict__ a_s4,
                                             const float* __restrict__ a_d4, const unsigned* __restrict__ asmaxk,
                                             const float* __restrict__ b2, float* __restrict__ out, int n) {
    int w = (blockIdx.x * 256 + threadIdx.x) >> 6;
    int lane = threadIdx.x & 63;
    if (w >= n) return;
    bool act = lane < 48;
    int ll = act ? lane : (lane - 48);
    int hd = ll >> 4;
    int c4 = ll * 4;

    float adh = a_d4[w * 4 + hd];
    float Ch  = lrelu(fdec(asmaxk[hd]) + adh);
    float ash = a_s4[w * 4 + hd];
    float wsl = __expf(lrelu(ash + adh) - Ch);     // self-loop weight
    float ssum = wsl;
    half4_t hv = *(const half4_t*)(h2h + ((size_t)w << 8) + c4);
    float a0 = wsl * (float)hv[0], a1 = wsl * (float)hv[1];
    float a2 = wsl * (float)hv[2], a3 = wsl * (float)hv[3];

    int beg = off[w], end = off[w + 1];
    int i = beg;
    for (; i + 4 <= end; i += 4) {
        int sA = csr[i], sB = csr[i + 1], sC = csr[i + 2], sD = csr[i + 3];
        float eA = a_s4[(size_t)sA * 4 + hd];
        float eB = a_s4[(size_t)sB * 4 + hd];
        float eC = a_s4[(size_t)sC * 4 + hd];
        float eD = a_s4[(size_t)sD * 4 + hd];
        half4_t hA = *(const half4_t*)(h2h + ((size_t)sA << 8) + c4);
        half4_t hB = *(const half4_t*)(h2h + ((size_t)sB << 8) + c4);
        half4_t hC = *(const half4_t*)(h2h + ((size_t)sC << 8) + c4);
        half4_t hD = *(const half4_t*)(h2h + ((size_t)sD << 8) + c4);
        GAT_EDGE(eA, hA); GAT_EDGE(eB, hB); GAT_EDGE(eC, hC); GAT_EDGE(eD, hD);
    }
    for (; i < end; i++) {
        int s = csr[i];
        float ev = a_s4[(size_t)s * 4 + hd];
        half4_t hx = *(const half4_t*)(h2h + ((size_t)s << 8) + c4);
        GAT_EDGE(ev, hx);
    }

    if (act) {
        float inv = 1.f / ssum;
        float4 bb = *(const float4*)(b2 + c4);
        float4 o;
        o.x = fmaxf(fmaf(a0, inv, bb.x), 0.f);
        o.y = fmaxf(fmaf(a1, inv, bb.y), 0.f);
        o.z = fmaxf(fmaf(a2, inv, bb.z), 0.f);
        o.w = fmaxf(fmaf(a3, inv, bb.w), 0.f);
        *(float4*)(out + (size_t)w * OC + c4) = o;
    }
}

// ---------------- launcher ----------------
extern "C" void kernel_launch(void* const* d_in, const int* in_sizes, int n_in,
                              void* d_out, int out_size, void* d_ws, size_t ws_size,
                              hipStream_t stream) {
    const float* x        = (const float*)d_in[0];
    const int*   ei       = (const int*)d_in[1];
    const float* W1       = (const float*)d_in[2];
    const float* b1       = (const float*)d_in[3];
    const float* W2       = (const float*)d_in[4];
    const float* att_src  = (const float*)d_in[5];
    const float* att_dst  = (const float*)d_in[6];
    const float* b2       = (const float*)d_in[7];
    float* out = (float*)d_out;

    const int n = in_sizes[0] / IN_CH;     // 50000
    const int E = in_sizes[1] / 2;         // 800000
    const int* src = ei;
    const int* dst = ei + E;

    // workspace layout (bytes), 256-aligned
    char* ws = (char*)d_ws;
    int*            cnt    = (int*)(ws + 0);               // 50000 i   (memset 0)
    int*            fill   = (int*)(ws + 200704);          // 50000 i   (memset 0)
    unsigned*       asmaxk = (unsigned*)(ws + 401408);     // 3 u       (memset 0)
    int*            off    = (int*)(ws + 401664);          // 50001 i
    float*          dinv   = (float*)(ws + 602368);        // 50000 f
    int*            bsum   = (int*)(ws + 803072);          // 49 i
    int*            bbase  = (int*)(ws + 803328);          // 64 i
    _Float16*       W1t    = (_Float16*)(ws + 803584);     // 128*256 h
    _Float16*       W2t    = (_Float16*)(ws + 869120);     // 192*128 h
    unsigned short* csr    = (unsigned short*)(ws + 918528); // 800000 u16 = 1.6 MB
    float*          a_s4   = (float*)(ws + 2518528);       // 50000*4 f
    float*          a_d4   = (float*)(ws + 3318528);       // 50000*4 f
    _Float16*       xwh    = (_Float16*)(ws + 4118528);    // 50000*128 h (pre-scaled by dinv)
    _Float16*       hh     = (_Float16*)(ws + 16918528);   // 50000*128 h
    _Float16*       h2h    = (_Float16*)(ws + 29718528);   // 50000*256 h (rows padded to 512B)
    // total ~55 MB

    (void)hipMemsetAsync(ws, 0, 401424, stream);     // cnt + fill + asmaxk

    int egrid = (E + 255) / 256;                     // 3125 (covers cvt range 81920 too)
    int nb = (n + 1023) / 1024;                      // 49
    int gm = (n + 63) / 64;                          // 782
    k_hist<<<egrid, 256, 0, stream>>>(dst, E, cnt, W1, W2, W1t, W2t);
    k_scanA<<<nb, 1024, 0, stream>>>(cnt, off, dinv, bsum, n);
    k_scanB<<<1, 64, 0, stream>>>(bsum, bbase, off, nb, n);
    k_scanC<<<(n + 255) / 256, 256, 0, stream>>>(off, bbase, n);

    // merged fill + gemm1 (independent work, co-scheduled in one dispatch)
    k_fillg1<<<egrid + gm, 256, 0, stream>>>(src, dst, E, off, fill, csr,
                                             x, W1t, dinv, xwh, n, egrid);

    int ngrid = (n + 3) / 4;   // 4 waves per block
    k_gcn<<<ngrid, 256, 0, stream>>>(xwh, csr, off, dinv, b1, hh, n);

    k_gemm2m<<<gm, 256, 0, stream>>>(hh, W2t, h2h, n);

    k_att<<<ngrid, 256, 0, stream>>>(h2h, att_src, att_dst, a_s4, a_d4, n);
    k_asmax<<<nb, 1024, 0, stream>>>(a_s4, n, asmaxk);
    k_gat<<<ngrid, 256, 0, stream>>>(h2h, csr, off, a_s4, a_d4, asmaxk, b2, out, n);
}

// Round 15
// 224.318 us; speedup vs baseline: 2.0829x; 1.1218x over previous
//
#include <hip/hip_runtime.h>
#include <hip/hip_fp16.h>
#include <math.h>

// Problem constants (verified against reference setup_inputs)
#define NODES    50000
#define IN_CH    256
#define HID      128
#define HEADS    3
#define HC       64
#define OC       (HEADS*HC)   // 192
#define NEG_SLOPE 0.2f

typedef _Float16 half8_t __attribute__((ext_vector_type(8)));
typedef _Float16 half4_t __attribute__((ext_vector_type(4)));
typedef float float4_t __attribute__((ext_vector_type(4)));

__device__ __forceinline__ float lrelu(float v) { return v > 0.f ? v : NEG_SLOPE * v; }

// monotone unsigned key for float max-atomics (fkey(finite) > 0, so memset-0 is identity)
__device__ __forceinline__ unsigned fkey(float f) {
    unsigned b = __float_as_uint(f);
    return (b & 0x80000000u) ? ~b : (b | 0x80000000u);
}
__device__ __forceinline__ float fdec(unsigned k) {
    unsigned b = (k & 0x80000000u) ? (k ^ 0x80000000u) : ~k;
    return __uint_as_float(b);
}

// ---------------- CSR build ----------------
// k_hist: histogram AND capture each edge's arrival rank within its dst segment.
// The rank makes k_fill atomic-free. Also does the weight fp16-transpose prepass.
__global__ __launch_bounds__(256) void k_hist(const int* __restrict__ dst, int E, int* __restrict__ cnt,
                                              unsigned short* __restrict__ rank,
                                              const float* __restrict__ W1, const float* __restrict__ W2,
                                              _Float16* __restrict__ W1t, _Float16* __restrict__ W2t) {
    int e = blockIdx.x * 256 + threadIdx.x;
    if (e < E) {
        int r = atomicAdd(&cnt[dst[e]], 1);
        rank[e] = (unsigned short)r;
    }
    if (e < IN_CH * HID) {
        int c = e >> 8, k = e & 255;                 // W1t[c][k] = W1[k][c]
        W1t[e] = (_Float16)W1[(size_t)k * HID + c];
    } else if (e < IN_CH * HID + HID * OC) {
        int u = e - IN_CH * HID;
        int c = u >> 7, k = u & 127;                 // W2t[c][k] = W2[k][c]
        W2t[u] = (_Float16)W2[(size_t)k * OC + c];
    }
}

__global__ __launch_bounds__(1024) void k_scanA(const int* __restrict__ cnt, int* __restrict__ off,
                                                float* __restrict__ dinv, int* __restrict__ bsum, int n) {
    __shared__ int wsums[16];
    int tid = threadIdx.x, lane = tid & 63, wid = tid >> 6;
    int i = blockIdx.x * 1024 + tid;
    int v = (i < n) ? cnt[i] : 0;
    int incl = v;
    #pragma unroll
    for (int d = 1; d < 64; d <<= 1) {
        int t = __shfl_up(incl, d, 64);
        if (lane >= d) incl += t;
    }
    if (lane == 63) wsums[wid] = incl;
    __syncthreads();
    if (tid == 0) {
        int run = 0;
        #pragma unroll
        for (int j = 0; j < 16; j++) { int t = wsums[j]; wsums[j] = run; run += t; }
        bsum[blockIdx.x] = run;
    }
    __syncthreads();
    if (i < n) {
        off[i] = wsums[wid] + incl - v;
        dinv[i] = rsqrtf((float)(v + 1));   // +1 for self loop
    }
}

__global__ __launch_bounds__(64) void k_scanB(const int* __restrict__ bsum, int* __restrict__ bbase,
                                              int* __restrict__ off, int nb, int n) {
    int tid = threadIdx.x;
    int v = (tid < nb) ? bsum[tid] : 0;
    int incl = v;
    #pragma unroll
    for (int d = 1; d < 64; d <<= 1) {
        int t = __shfl_up(incl, d, 64);
        if (tid >= d) incl += t;
    }
    bbase[tid] = incl - v;
    if (tid == 63) off[n] = incl;   // grand total = E
}

__global__ __launch_bounds__(256) void k_scanC(int* __restrict__ off, const int* __restrict__ bbase, int n) {
    int i = blockIdx.x * 256 + threadIdx.x;
    if (i < n) off[i] += bbase[i >> 10];
}

// ---------------- MERGED: atomic-free fill (blocks [0, fillBlocks)) + GEMM1 (rest) ----------------
__global__ __launch_bounds__(256) void k_fillg1(const int* __restrict__ src, const int* __restrict__ dst, int E,
                                                const int* __restrict__ off, const unsigned short* __restrict__ rank,
                                                unsigned short* __restrict__ csr,
                                                const float* __restrict__ x, const _Float16* __restrict__ W1t,
                                                const float* __restrict__ dinv, _Float16* __restrict__ xwh,
                                                int n, int fillBlocks) {
    if ((int)blockIdx.x < fillBlocks) {
        int e = blockIdx.x * 256 + threadIdx.x;
        if (e < E) {
            int d = dst[e];
            int p = off[d] + (int)rank[e];      // no atomic: rank captured in k_hist
            csr[p] = (unsigned short)src[e];
        }
        return;
    }

    // ---- GEMM1 (MFMA): xwh = fp16( dinv[row] * (x @ W1) ) ----
    int bid = blockIdx.x - fillBlocks;
    int wid = threadIdx.x >> 6, lane = threadIdx.x & 63;
    int lrow = lane & 15, kgrp = lane >> 4;          // A: row=lrow, k-chunk=kgrp*8
    int arow = bid * 64 + wid * 16 + lrow;
    bool rv = arow < n;
    const float* xp = x + (size_t)arow * IN_CH + kgrp * 8;

    float4_t acc[8];
    #pragma unroll
    for (int s = 0; s < 8; s++) acc[s] = (float4_t)(0.f);

    #pragma unroll
    for (int kc = 0; kc < IN_CH; kc += 32) {
        float4 a0, a1;
        if (rv) { a0 = *(const float4*)(xp + kc); a1 = *(const float4*)(xp + kc + 4); }
        else { a0 = make_float4(0.f,0.f,0.f,0.f); a1 = a0; }
        half8_t af;
        af[0]=(_Float16)a0.x; af[1]=(_Float16)a0.y; af[2]=(_Float16)a0.z; af[3]=(_Float16)a0.w;
        af[4]=(_Float16)a1.x; af[5]=(_Float16)a1.y; af[6]=(_Float16)a1.z; af[7]=(_Float16)a1.w;
        #pragma unroll
        for (int s = 0; s < 8; s++) {
            const _Float16* bp = W1t + (size_t)(s * 16 + lrow) * IN_CH + kc + kgrp * 8;
            half8_t bf = *(const half8_t*)bp;
            acc[s] = __builtin_amdgcn_mfma_f32_16x16x32_f16(af, bf, acc[s], 0, 0, 0);
        }
    }

    // C/D: col = lane&15 (=lrow), row = kgrp*4 + r
    int orow0 = bid * 64 + wid * 16 + kgrp * 4;
    #pragma unroll
    for (int r = 0; r < 4; r++) {
        int orow = orow0 + r;
        if (orow < n) {
            float sc = dinv[orow];
            _Float16* po = xwh + ((size_t)orow << 7) + lrow;
            #pragma unroll
            for (int s = 0; s < 8; s++) po[s * 16] = (_Float16)(sc * acc[s][r]);
        }
    }
}

// ---------------- GCN aggregate: wave/node, 16 lanes/edge x half8, fp16 pair-add ----------------
__global__ __launch_bounds__(256) void k_gcn(const _Float16* __restrict__ xwh, const unsigned short* __restrict__ csr,
                                             const int* __restrict__ off, const float* __restrict__ dinv,
                                             const float* __restrict__ b1, _Float16* __restrict__ hh, int n) {
    int w = (blockIdx.x * 256 + threadIdx.x) >> 6;
    int lane = threadIdx.x & 63;
    if (w >= n) return;
    int egrp = lane >> 4;          // which of 4 edges this lane serves
    int c8 = (lane & 15) * 8;      // 8 contiguous cols
    float acc[8];
    #pragma unroll
    for (int j = 0; j < 8; j++) acc[j] = 0.f;

    int beg = off[w], end = off[w + 1];
    int i = beg;
    for (; i + 16 <= end; i += 16) {
        int s0 = csr[i + egrp];
        int s1 = csr[i + 4 + egrp];
        int s2 = csr[i + 8 + egrp];
        int s3 = csr[i + 12 + egrp];
        half8_t v0 = *(const half8_t*)(xwh + ((size_t)s0 << 7) + c8);
        half8_t v1 = *(const half8_t*)(xwh + ((size_t)s1 << 7) + c8);
        half8_t v2 = *(const half8_t*)(xwh + ((size_t)s2 << 7) + c8);
        half8_t v3 = *(const half8_t*)(xwh + ((size_t)s3 << 7) + c8);
        half8_t p01 = v0 + v1;          // v_pk_add_f16 (error ~ulp, shrunk by dinv later)
        half8_t p23 = v2 + v3;
        #pragma unroll
        for (int j = 0; j < 8; j++)
            acc[j] += (float)p01[j] + (float)p23[j];
    }
    for (; i + 4 <= end; i += 4) {
        int s = csr[i + egrp];
        half8_t v = *(const half8_t*)(xwh + ((size_t)s << 7) + c8);
        #pragma unroll
        for (int j = 0; j < 8; j++) acc[j] += (float)v[j];
    }
    if (i < end && egrp < (end - i)) {
        int s = csr[i + egrp];
        half8_t v = *(const half8_t*)(xwh + ((size_t)s << 7) + c8);
        #pragma unroll
        for (int j = 0; j < 8; j++) acc[j] += (float)v[j];
    }

    #pragma unroll
    for (int j = 0; j < 8; j++) {
        acc[j] += __shfl_xor(acc[j], 16, 64);
        acc[j] += __shfl_xor(acc[j], 32, 64);
    }
    if (egrp == 0) {
        float di = dinv[w];
        half8_t self = *(const half8_t*)(xwh + ((size_t)w << 7) + c8);
        float4 bb0 = *(const float4*)(b1 + c8);
        float4 bb1 = *(const float4*)(b1 + c8 + 4);
        float bv[8] = {bb0.x, bb0.y, bb0.z, bb0.w, bb1.x, bb1.y, bb1.z, bb1.w};
        half8_t o;
        #pragma unroll
        for (int j = 0; j < 8; j++)
            o[j] = (_Float16)fmaxf(fmaf(di, acc[j] + (float)self[j], bv[j]), 0.f);
        *(half8_t*)(hh + ((size_t)w << 7) + c8) = o;
    }
}

// ---------------- GEMM2 (MFMA): h2h[pad 256] = fp16( h @ W2 )  [N,128]x[128,192] ----------------
__global__ __launch_bounds__(256) void k_gemm2m(const _Float16* __restrict__ hh, const _Float16* __restrict__ W2t,
                                                _Float16* __restrict__ h2h, int n) {
    int wid = threadIdx.x >> 6, lane = threadIdx.x & 63;
    int lrow = lane & 15, kgrp = lane >> 4;
    int arow = blockIdx.x * 64 + wid * 16 + lrow;
    bool rv = arow < n;
    const _Float16* hp = hh + ((size_t)arow << 7) + kgrp * 8;

    float4_t acc[12];
    #pragma unroll
    for (int s = 0; s < 12; s++) acc[s] = (float4_t)(0.f);

    #pragma unroll
    for (int kc = 0; kc < HID; kc += 32) {
        half8_t af = (half8_t)((_Float16)0.f);
        if (rv) af = *(const half8_t*)(hp + kc);
        #pragma unroll
        for (int s = 0; s < 12; s++) {
            const _Float16* bp = W2t + (size_t)(s * 16 + lrow) * HID + kc + kgrp * 8;
            half8_t bf = *(const half8_t*)bp;
            acc[s] = __builtin_amdgcn_mfma_f32_16x16x32_f16(af, bf, acc[s], 0, 0, 0);
        }
    }

    int orow0 = blockIdx.x * 64 + wid * 16 + kgrp * 4;
    #pragma unroll
    for (int r = 0; r < 4; r++) {
        int orow = orow0 + r;
        if (orow < n) {
            _Float16* po = h2h + ((size_t)orow << 8) + lrow;
            #pragma unroll
            for (int s = 0; s < 12; s++) po[s * 16] = (_Float16)acc[s][r];
        }
    }
}

// ---------------- attention scores: 48 lanes cover all 192 cols, 3 heads concurrent ----------------
__global__ __launch_bounds__(256) void k_att(const _Float16* __restrict__ h2h, const float* __restrict__ att_s,
                                             const float* __restrict__ att_d, float* __restrict__ a_s4,
                                             float* __restrict__ a_d4, int n) {
    int w = (blockIdx.x * 256 + threadIdx.x) >> 6;
    int lane = threadIdx.x & 63;
    if (w >= n) return;
    bool act = lane < 48;
    int ll = act ? lane : (lane - 48);
    int hd = ll >> 4;
    int c4 = ll * 4;

    half4_t hv = *(const half4_t*)(h2h + ((size_t)w << 8) + c4);
    float4 as = *(const float4*)(att_s + c4);
    float4 ad = *(const float4*)(att_d + c4);
    float vs = (float)hv[0] * as.x + (float)hv[1] * as.y + (float)hv[2] * as.z + (float)hv[3] * as.w;
    float vd = (float)hv[0] * ad.x + (float)hv[1] * ad.y + (float)hv[2] * ad.z + (float)hv[3] * ad.w;
    #pragma unroll
    for (int o = 1; o < 16; o <<= 1) {
        vs += __shfl_xor(vs, o, 64);
        vd += __shfl_xor(vd, o, 64);
    }
    if (act && (ll & 15) == 0) {
        a_s4[w * 4 + hd] = vs;
        a_d4[w * 4 + hd] = vd;
    }
}

// ---------------- global per-head max of a_s (multi-block + fkey atomicMax) ----------------
__global__ __launch_bounds__(1024) void k_asmax(const float* __restrict__ a_s4, int n, unsigned* __restrict__ asmaxk) {
    int i = blockIdx.x * 1024 + threadIdx.x;
    float m0 = -1e30f, m1 = -1e30f, m2 = -1e30f;
    if (i < n) {
        float4 v = *(const float4*)(a_s4 + (size_t)i * 4);
        m0 = v.x; m1 = v.y; m2 = v.z;
    }
    #pragma unroll
    for (int o = 32; o > 0; o >>= 1) {
        m0 = fmaxf(m0, __shfl_xor(m0, o, 64));
        m1 = fmaxf(m1, __shfl_xor(m1, o, 64));
        m2 = fmaxf(m2, __shfl_xor(m2, o, 64));
    }
    __shared__ float sm[16][3];
    int lane = threadIdx.x & 63, wid = threadIdx.x >> 6;
    if (lane == 0) { sm[wid][0] = m0; sm[wid][1] = m1; sm[wid][2] = m2; }
    __syncthreads();
    if (threadIdx.x == 0) {
        for (int j = 1; j < 16; j++) {
            m0 = fmaxf(m0, sm[j][0]); m1 = fmaxf(m1, sm[j][1]); m2 = fmaxf(m2, sm[j][2]);
        }
        atomicMax(asmaxk + 0, fkey(m0));
        atomicMax(asmaxk + 1, fkey(m1));
        atomicMax(asmaxk + 2, fkey(m2));
    }
}

// ---------------- GAT aggregate: wave/node, inline weights, fma_mix on raw fp16, unroll-4 ----------------
#define GAT_EDGE(ev, hv) do { \
    float wl = __expf(lrelu((ev) + adh) - Ch); \
    ssum += wl; \
    a0 = fmaf(wl, (float)(hv)[0], a0); \
    a1 = fmaf(wl, (float)(hv)[1], a1); \
    a2 = fmaf(wl, (float)(hv)[2], a2); \
    a3 = fmaf(wl, (float)(hv)[3], a3); \
} while (0)

__global__ __launch_bounds__(256) void k_gat(const _Float16* __restrict__ h2h, const unsigned short* __restrict__ csr,
                                             const int* __restrict__ off, const float* __restrict__ a_s4,
                                             const float* __restrict__ a_d4, const unsigned* __restrict__ asmaxk,
                                             const float* __restrict__ b2, float* __restrict__ out, int n) {
    int w = (blockIdx.x * 256 + threadIdx.x) >> 6;
    int lane = threadIdx.x & 63;
    if (w >= n) return;
    bool act = lane < 48;
    int ll = act ? lane : (lane - 48);
    int hd = ll >> 4;
    int c4 = ll * 4;

    float adh = a_d4[w * 4 + hd];
    float Ch  = lrelu(fdec(asmaxk[hd]) + adh);
    float ash = a_s4[w * 4 + hd];
    float wsl = __expf(lrelu(ash + adh) - Ch);     // self-loop weight
    float ssum = wsl;
    half4_t hv = *(const half4_t*)(h2h + ((size_t)w << 8) + c4);
    float a0 = wsl * (float)hv[0], a1 = wsl * (float)hv[1];
    float a2 = wsl * (float)hv[2], a3 = wsl * (float)hv[3];

    int beg = off[w], end = off[w + 1];
    int i = beg;
    for (; i + 4 <= end; i += 4) {
        int sA = csr[i], sB = csr[i + 1], sC = csr[i + 2], sD = csr[i + 3];
        float eA = a_s4[(size_t)sA * 4 + hd];
        float eB = a_s4[(size_t)sB * 4 + hd];
        float eC = a_s4[(size_t)sC * 4 + hd];
        float eD = a_s4[(size_t)sD * 4 + hd];
        half4_t hA = *(const half4_t*)(h2h + ((size_t)sA << 8) + c4);
        half4_t hB = *(const half4_t*)(h2h + ((size_t)sB << 8) + c4);
        half4_t hC = *(const half4_t*)(h2h + ((size_t)sC << 8) + c4);
        half4_t hD = *(const half4_t*)(h2h + ((size_t)sD << 8) + c4);
        GAT_EDGE(eA, hA); GAT_EDGE(eB, hB); GAT_EDGE(eC, hC); GAT_EDGE(eD, hD);
    }
    for (; i < end; i++) {
        int s = csr[i];
        float ev = a_s4[(size_t)s * 4 + hd];
        half4_t hx = *(const half4_t*)(h2h + ((size_t)s << 8) + c4);
        GAT_EDGE(ev, hx);
    }

    if (act) {
        float inv = 1.f / ssum;
        float4 bb = *(const float4*)(b2 + c4);
        float4 o;
        o.x = fmaxf(fmaf(a0, inv, bb.x), 0.f);
        o.y = fmaxf(fmaf(a1, inv, bb.y), 0.f);
        o.z = fmaxf(fmaf(a2, inv, bb.z), 0.f);
        o.w = fmaxf(fmaf(a3, inv, bb.w), 0.f);
        *(float4*)(out + (size_t)w * OC + c4) = o;
    }
}

// ---------------- launcher ----------------
extern "C" void kernel_launch(void* const* d_in, const int* in_sizes, int n_in,
                              void* d_out, int out_size, void* d_ws, size_t ws_size,
                              hipStream_t stream) {
    const float* x        = (const float*)d_in[0];
    const int*   ei       = (const int*)d_in[1];
    const float* W1       = (const float*)d_in[2];
    const float* b1       = (const float*)d_in[3];
    const float* W2       = (const float*)d_in[4];
    const float* att_src  = (const float*)d_in[5];
    const float* att_dst  = (const float*)d_in[6];
    const float* b2       = (const float*)d_in[7];
    float* out = (float*)d_out;

    const int n = in_sizes[0] / IN_CH;     // 50000
    const int E = in_sizes[1] / 2;         // 800000
    const int* src = ei;
    const int* dst = ei + E;

    // workspace layout (bytes), 256-aligned
    char* ws = (char*)d_ws;
    int*            cnt    = (int*)(ws + 0);               // 50000 i   (memset 0)
    unsigned*       asmaxk = (unsigned*)(ws + 200704);     // 3 u       (memset 0)
    int*            off    = (int*)(ws + 200960);          // 50001 i
    float*          dinv   = (float*)(ws + 401664);        // 50000 f
    int*            bsum   = (int*)(ws + 602368);          // 49 i
    int*            bbase  = (int*)(ws + 602624);          // 64 i
    _Float16*       W1t    = (_Float16*)(ws + 602880);     // 128*256 h
    _Float16*       W2t    = (_Float16*)(ws + 668416);     // 192*128 h
    unsigned short* csr    = (unsigned short*)(ws + 717568);  // 800000 u16
    unsigned short* rank   = (unsigned short*)(ws + 2317568); // 800000 u16
    float*          a_s4   = (float*)(ws + 3917568);       // 50000*4 f
    float*          a_d4   = (float*)(ws + 4717568);       // 50000*4 f
    _Float16*       xwh    = (_Float16*)(ws + 5517568);    // 50000*128 h (pre-scaled by dinv)
    _Float16*       hh     = (_Float16*)(ws + 18317568);   // 50000*128 h
    _Float16*       h2h    = (_Float16*)(ws + 31117568);   // 50000*256 h (rows padded to 512B)
    // total ~57 MB

    (void)hipMemsetAsync(ws, 0, 200720, stream);     // cnt + asmaxk

    int egrid = (E + 255) / 256;                     // 3125 (covers cvt range 81920 too)
    int nb = (n + 1023) / 1024;                      // 49
    int gm = (n + 63) / 64;                          // 782
    k_hist<<<egrid, 256, 0, stream>>>(dst, E, cnt, rank, W1, W2, W1t, W2t);
    k_scanA<<<nb, 1024, 0, stream>>>(cnt, off, dinv, bsum, n);
    k_scanB<<<1, 64, 0, stream>>>(bsum, bbase, off, nb, n);
    k_scanC<<<(n + 255) / 256, 256, 0, stream>>>(off, bbase, n);

    // merged atomic-free fill + gemm1 (independent work, co-scheduled in one dispatch)
    k_fillg1<<<egrid + gm, 256, 0, stream>>>(src, dst, E, off, rank, csr,
                                             x, W1t, dinv, xwh, n, egrid);

    int ngrid = (n + 3) / 4;   // 4 waves per block
    k_gcn<<<ngrid, 256, 0, stream>>>(xwh, csr, off, dinv, b1, hh, n);

    k_gemm2m<<<gm, 256, 0, stream>>>(hh, W2t, h2h, n);

    k_att<<<ngrid, 256, 0, stream>>>(h2h, att_src, att_dst, a_s4, a_d4, n);
    k_asmax<<<nb, 1024, 0, stream>>>(a_s4, n, asmaxk);
    k_gat<<<ngrid, 256, 0, stream>>>(h2h, csr, off, a_s4, a_d4, asmaxk, b2, out, n);
}